// Round 6
// baseline (1089.624 us; speedup 1.0000x reference)
//
#include <hip/hip_runtime.h>

#define B_ 2
#define C_ 256
#define H_ 192
#define W_ 256
#define HW_ 49152
#define T_ 98304

typedef __bf16 bf16x8 __attribute__((ext_vector_type(8)));
typedef float  f32x4  __attribute__((ext_vector_type(4)));
typedef short  s16x8  __attribute__((ext_vector_type(8)));

__device__ inline unsigned short f2bf(float f) {
    unsigned u = __float_as_uint(f);
    u = u + 0x7fffu + ((u >> 16) & 1u);
    return (unsigned short)(u >> 16);
}
__device__ inline float bf2f(unsigned short u) {
    return __uint_as_float(((unsigned)u) << 16);
}
__device__ inline unsigned short bfbits(float f) {
    __bf16 h = (__bf16)f;
    return __builtin_bit_cast(unsigned short, h);
}
// async global->LDS, 16B per lane; LDS dest = base + lane*16 (HW rule)
__device__ inline void gload_lds16(const unsigned short* g, short* l) {
    __builtin_amdgcn_global_load_lds(
        (const __attribute__((address_space(1))) unsigned int*)g,
        (__attribute__((address_space(3))) unsigned int*)l, 16, 0, 0);
}

// ============================ weight fp32 -> bf16 ============================
__global__ __launch_bounds__(256) void wcvt_kernel(
    const float* __restrict__ in, unsigned short* __restrict__ out, int n)
{
    int i = (blockIdx.x * 256 + threadIdx.x) * 4;
    if (i >= n) return;
    float4 v = *(const float4*)(in + i);
    out[i + 0] = f2bf(v.x);
    out[i + 1] = f2bf(v.y);
    out[i + 2] = f2bf(v.z);
    out[i + 3] = f2bf(v.w);
}

// ============================ LN1 stats ============================
__global__ __launch_bounds__(256) void ln1_stats_kernel(
    const float* __restrict__ x, float* __restrict__ mean, float* __restrict__ rstd)
{
    int t = blockIdx.x * 256 + threadIdx.x;
    int b = t / HW_;
    int hw = t - b * HW_;
    const float* p = x + (size_t)b * C_ * HW_ + hw;
    float s = 0.f, q = 0.f;
    for (int c = 0; c < C_; ++c) {
        float v = p[(size_t)c * HW_];
        s += v; q += v * v;
    }
    float m = s * (1.f / C_);
    float var = q * (1.f / C_) - m * m;
    mean[t] = m;
    rstd[t] = rsqrtf(var + 1e-5f);
}

// ============================ x -> LN1(x) bf16 row-major ============================
__global__ __launch_bounds__(256) void xln_kernel(
    const float* __restrict__ x, const float* __restrict__ mean,
    const float* __restrict__ rstd, const float* __restrict__ g,
    const float* __restrict__ bta, unsigned short* __restrict__ xn)
{
    __shared__ float tile[32][33];
    int t0 = blockIdx.x * 32;
    int c0 = blockIdx.y * 32;
    int b = t0 / HW_, hw0 = t0 - b * HW_;
    int tid = threadIdx.x, lane = tid & 31, grp = tid >> 5;
    float mm = mean[t0 + lane], rr = rstd[t0 + lane];
    #pragma unroll
    for (int j = 0; j < 4; ++j) {
        int c = grp + j * 8;
        float v = x[((size_t)b * C_ + c0 + c) * HW_ + hw0 + lane];
        tile[c][lane] = (v - mm) * rr;
    }
    __syncthreads();
    float gg = g[c0 + lane], bb = bta[c0 + lane];
    #pragma unroll
    for (int j = 0; j < 4; ++j) {
        int tt = grp + j * 8;
        xn[(size_t)(t0 + tt) * C_ + c0 + lane] = f2bf(tile[lane][tt] * gg + bb);
    }
}

// ============================ LN2: fused stats + normalize -> bf16 ============================
__global__ __launch_bounds__(256) void ln2norm_kernel(
    const float* __restrict__ xr, const float* __restrict__ g,
    const float* __restrict__ bta, unsigned short* __restrict__ out)
{
    int wv = threadIdx.x >> 6, lane = threadIdx.x & 63;
    int t = blockIdx.x * 4 + wv;
    const float4 v = *(const float4*)(xr + (size_t)t * C_ + lane * 4);
    float s = v.x + v.y + v.z + v.w;
    float q = v.x * v.x + v.y * v.y + v.z * v.z + v.w * v.w;
    #pragma unroll
    for (int o = 32; o > 0; o >>= 1) {
        s += __shfl_xor(s, o);
        q += __shfl_xor(q, o);
    }
    float m = s * (1.f / C_);
    float r = rsqrtf(q * (1.f / C_) - m * m + 1e-5f);
    float4 gg = *(const float4*)(g + lane * 4);
    float4 bb = *(const float4*)(bta + lane * 4);
    unsigned short o0 = f2bf((v.x - m) * r * gg.x + bb.x);
    unsigned short o1 = f2bf((v.y - m) * r * gg.y + bb.y);
    unsigned short o2 = f2bf((v.z - m) * r * gg.z + bb.z);
    unsigned short o3 = f2bf((v.w - m) * r * gg.w + bb.w);
    unsigned lo = ((unsigned)o1 << 16) | o0;
    unsigned hi = ((unsigned)o3 << 16) | o2;
    *(uint2*)(out + (size_t)t * C_ + lane * 4) = make_uint2(lo, hi);
}

// ============================ MFMA GEMM (dbuf + prefetch pipeline) ============================
// C[M,N] = A[M,K] @ W[N,K]^T (+ epilogue). bf16 in, fp32 acc.
// 128x128 tile, BK=32, 4 waves (2x2), each wave 4x4 frags of 16x16x32.
// LDS subtile s (16 rows): lane l holds (row = l&15, k = (l>>4)*8+j) at
// shorts [s][l*8+j] == base + l*16B -> matches global_load_lds lane rule.
// T3 2-phase pipeline: STAGE(next) issued BEFORE compute(cur); the single
// end-of-iter barrier (implicit vmcnt(0)) finds next-tile loads landed.
enum { AB_ROW = 0, AB_CAT = 1, AB_GATHER = 2 };
enum { EB_BF16 = 0, EB_F32 = 1, EG_BF16 = 2, ER_F32 = 3, ER_PLANAR = 4 };

template<int AMODE, int EMODE>
__global__ __launch_bounds__(256) void mgemm(
    const unsigned short* __restrict__ A0, const unsigned short* __restrict__ A1,
    const unsigned short* __restrict__ Wb, const float* __restrict__ bias,
    const float* __restrict__ resid, float* __restrict__ outf,
    unsigned short* __restrict__ outb,
    int K, int lda, int ldw, int ldo, int rowoff)
{
    __shared__ __align__(16) short As[2][8][512];
    __shared__ __align__(16) short Bs[2][8][512];
    const int tid = threadIdx.x;
    const int t0 = blockIdx.x * 128;
    const int n0 = blockIdx.y * 128;
    const int lane = tid & 63, wv = tid >> 6;
    const int wr = wv >> 1, wc = wv & 1;
    const int fr = lane & 15;          // row/col within subtile
    const int fk = (lane >> 4) * 8;    // k offset within BK

    // hoisted per-lane source pointers (k-independent part)
    const unsigned short* aptr0 = nullptr;
    const unsigned short* aptr1 = nullptr;
    if (AMODE == AB_GATHER) {
        #pragma unroll
        for (int si = 0; si < 2; ++si) {
            const int gr = rowoff + t0 + (wv * 2 + si) * 16 + fr;
            const int b = gr / HW_;
            const int rem = gr - b * HW_;
            const int w = rem / H_;
            const int h = rem - w * H_;
            const unsigned short* p =
                A0 + ((size_t)b * HW_ + (size_t)h * W_ + w) * 256 + 128 + fk;
            if (si == 0) aptr0 = p; else aptr1 = p;
        }
    } else if (AMODE == AB_ROW) {
        aptr0 = A0 + (size_t)(t0 + (wv * 2 + 0) * 16 + fr) * lda + fk;
        aptr1 = A0 + (size_t)(t0 + (wv * 2 + 1) * 16 + fr) * lda + fk;
    }
    const unsigned short* bptr0 = Wb + (size_t)(n0 + (wv * 2 + 0) * 16 + fr) * ldw + fk;
    const unsigned short* bptr1 = Wb + (size_t)(n0 + (wv * 2 + 1) * 16 + fr) * ldw + fk;

    f32x4 acc[4][4];
    #pragma unroll
    for (int m = 0; m < 4; ++m)
        #pragma unroll
        for (int n = 0; n < 4; ++n)
            acc[m][n] = (f32x4){0.f, 0.f, 0.f, 0.f};

    auto stage = [&](int buf, int k0) {
        if (AMODE == AB_CAT) {
            const unsigned short* base = (k0 < 128) ? A0 : A1;
            const int kk = (k0 & 127) + fk;
            gload_lds16(base + (size_t)(t0 + (wv * 2 + 0) * 16 + fr) * 128 + kk,
                        &As[buf][wv * 2 + 0][0]);
            gload_lds16(base + (size_t)(t0 + (wv * 2 + 1) * 16 + fr) * 128 + kk,
                        &As[buf][wv * 2 + 1][0]);
        } else {
            gload_lds16(aptr0 + k0, &As[buf][wv * 2 + 0][0]);
            gload_lds16(aptr1 + k0, &As[buf][wv * 2 + 1][0]);
        }
        gload_lds16(bptr0 + k0, &Bs[buf][wv * 2 + 0][0]);
        gload_lds16(bptr1 + k0, &Bs[buf][wv * 2 + 1][0]);
    };
    auto compute = [&](int buf) {
        bf16x8 af[4], bfr[4];
        #pragma unroll
        for (int m = 0; m < 4; ++m)
            af[m] = __builtin_bit_cast(bf16x8,
                *(const s16x8*)&As[buf][wr * 4 + m][lane * 8]);
        #pragma unroll
        for (int n = 0; n < 4; ++n)
            bfr[n] = __builtin_bit_cast(bf16x8,
                *(const s16x8*)&Bs[buf][wc * 4 + n][lane * 8]);
        #pragma unroll
        for (int m = 0; m < 4; ++m)
            #pragma unroll
            for (int n = 0; n < 4; ++n)
                acc[m][n] = __builtin_amdgcn_mfma_f32_16x16x32_bf16(
                    af[m], bfr[n], acc[m][n], 0, 0, 0);
    };

    // prologue
    stage(0, 0);
    __syncthreads();                 // implicit vmcnt(0): buf0 landed
    int cur = 0;
    for (int k0 = 32; k0 < K; k0 += 32) {
        stage(cur ^ 1, k0);          // prefetch next tile (flies under compute)
        compute(cur);
        __syncthreads();             // drains vmcnt: buf^1 ready, buf free
        cur ^= 1;
    }
    compute(cur);                    // last tile, no barrier needed

    // ---- epilogue: lane holds D[(lane>>4)*4 + r][lane&15] per fragment ----
    const int rowb = t0 + wr * 64 + (lane >> 4) * 4;
    const int colb = n0 + wc * 64 + (lane & 15);
    #pragma unroll
    for (int n = 0; n < 4; ++n) {
        const int col = colb + n * 16;
        const float bcol = bias[col];
        #pragma unroll
        for (int m = 0; m < 4; ++m) {
            const int row0 = rowb + m * 16;
            float4 rv = make_float4(0.f, 0.f, 0.f, 0.f);
            if (EMODE == ER_PLANAR) {
                const int bb = (row0 >= HW_) ? 1 : 0;
                const int hw = row0 - bb * HW_;
                rv = *(const float4*)(resid + ((size_t)bb * C_ + col) * HW_ + hw);
            }
            #pragma unroll
            for (int r = 0; r < 4; ++r) {
                const int row = row0 + r;
                float v = acc[m][n][r] + bcol;
                if (EMODE == EG_BF16)
                    v = 0.5f * v * (1.f + erff(v * 0.70710678118654752f));
                if (EMODE == ER_F32)
                    v += resid[(size_t)row * 256 + col];
                if (EMODE == ER_PLANAR)
                    v += (&rv.x)[r];
                if (EMODE == EB_F32 || EMODE == ER_F32 || EMODE == ER_PLANAR)
                    outf[(size_t)row * ldo + col] = v;
                else
                    outb[(size_t)row * ldo + col] = f2bf(v);
            }
        }
    }
}

// ============================ MFMA flash attention ============================
template<int N, int DIR>
__global__ __launch_bounds__(256) void attn_mfma_kernel(
    const unsigned short* __restrict__ qkv, unsigned short* __restrict__ outb, int strip0)
{
    constexpr int NT = N / 16;
    constexpr int CH = N / 32;
    constexpr int QTW = N / 64;
    constexpr int PST = N + 8;
    __shared__ __align__(16) short kls[NT * 256];
    __shared__ __align__(16) short vls[CH * 512];
    __shared__ __align__(16) short plds[4 * 16 * PST];
    const int head = blockIdx.x & 7;
    const int sl = blockIdx.x >> 3;
    const int s = strip0 + sl;
    const int tid = threadIdx.x;
    const unsigned short* base = qkv + (size_t)sl * N * 384;
    for (int i = tid; i < 2 * N; i += 256) {
        int r = i >> 1, hf = i & 1;
        s16x8 kv = *(const s16x8*)(base + (size_t)r * 384 + 128 + head * 16 + hf * 8);
        *(s16x8*)&kls[(r >> 4) * 256 + (hf * 16 + (r & 15)) * 8] = kv;
    }
    for (int i = tid; i < 2 * N; i += 256) {
        int r = i >> 1, hf = i & 1;
        s16x8 vv = *(const s16x8*)(base + (size_t)r * 384 + 256 + head * 16 + hf * 8);
        short* dst = &vls[(r >> 5) * 512 + ((r & 31) >> 3) * 128 + (r & 7)];
        #pragma unroll
        for (int j = 0; j < 8; ++j)
            dst[(hf * 8 + j) * 8] = vv[j];
    }
    __syncthreads();
    const int wv = tid >> 6, lane = tid & 63, g = lane >> 4, q = lane & 15;
    short* myP = &plds[wv * 16 * PST];
    const bf16x8 zf = __builtin_bit_cast(bf16x8, (s16x8){0,0,0,0,0,0,0,0});
    for (int qt_i = 0; qt_i < QTW; ++qt_i) {
        const int q0 = wv * (N / 4) + qt_i * 16;
        bf16x8 qf = zf;
        if (lane < 32)
            qf = __builtin_bit_cast(bf16x8,
                *(const s16x8*)(base + (size_t)(q0 + q) * 384 + head * 16 + g * 8));
        f32x4 sc[NT];
        #pragma unroll
        for (int n = 0; n < NT; ++n) {
            bf16x8 kf = zf;
            if (lane < 32)
                kf = __builtin_bit_cast(bf16x8, *(const s16x8*)&kls[n * 256 + lane * 8]);
            sc[n] = __builtin_amdgcn_mfma_f32_16x16x32_bf16(
                kf, qf, (f32x4){0.f, 0.f, 0.f, 0.f}, 0, 0, 0);
        }
        float mx = -3.0e38f;
        #pragma unroll
        for (int n = 0; n < NT; ++n)
            mx = fmaxf(mx, fmaxf(fmaxf(sc[n][0], sc[n][1]), fmaxf(sc[n][2], sc[n][3])));
        mx = fmaxf(mx, __shfl_xor(mx, 16));
        mx = fmaxf(mx, __shfl_xor(mx, 32));
        float sum = 0.f;
        #pragma unroll
        for (int n = 0; n < NT; ++n) {
            float p0 = __expf((sc[n][0] - mx) * 0.25f);
            float p1 = __expf((sc[n][1] - mx) * 0.25f);
            float p2 = __expf((sc[n][2] - mx) * 0.25f);
            float p3 = __expf((sc[n][3] - mx) * 0.25f);
            sum += (p0 + p1) + (p2 + p3);
            unsigned u01 = ((unsigned)bfbits(p1) << 16) | bfbits(p0);
            unsigned u23 = ((unsigned)bfbits(p3) << 16) | bfbits(p2);
            *(unsigned*)&myP[q * PST + n * 16 + g * 4] = u01;
            *(unsigned*)&myP[q * PST + n * 16 + g * 4 + 2] = u23;
        }
        sum += __shfl_xor(sum, 16);
        sum += __shfl_xor(sum, 32);
        const float inv = 1.f / sum;
        f32x4 o = (f32x4){0.f, 0.f, 0.f, 0.f};
        #pragma unroll
        for (int c = 0; c < CH; ++c) {
            bf16x8 vf = __builtin_bit_cast(bf16x8, *(const s16x8*)&vls[c * 512 + lane * 8]);
            bf16x8 pf = __builtin_bit_cast(bf16x8, *(const s16x8*)&myP[q * PST + c * 32 + g * 8]);
            o = __builtin_amdgcn_mfma_f32_16x16x32_bf16(vf, pf, o, 0, 0, 0);
        }
        unsigned lo = ((unsigned)bfbits(o[1] * inv) << 16) | bfbits(o[0] * inv);
        unsigned hi = ((unsigned)bfbits(o[3] * inv) << 16) | bfbits(o[2] * inv);
        size_t dst;
        if (DIR == 0) {
            dst = ((size_t)s * W_ + q0 + q) * 128 + head * 16 + g * 4;
        } else {
            int b = s >> 8, w = s & 255;
            dst = ((size_t)b * HW_ + (size_t)(q0 + q) * W_ + w) * 128 + head * 16 + g * 4;
        }
        *(uint2*)&outb[dst] = make_uint2(lo, hi);
    }
}

// ============================ PEG (depthwise 3x3 + residual) ============================
__global__ __launch_bounds__(256) void peg_kernel(
    const float* __restrict__ x2t, const float* __restrict__ pw,
    const float* __restrict__ pb, float* __restrict__ outp)
{
    __shared__ float pwt[9][132];
    __shared__ float tile[32][132];
    const int t0 = blockIdx.x * 32;
    const int cbase = blockIdx.y * 128;
    const int b = t0 / HW_, hw0 = t0 - b * HW_;
    const int h = hw0 >> 8, w0 = hw0 & 255;
    const int tid = threadIdx.x;
    for (int i = tid; i < 1152; i += 256) {
        int tap = i >> 7, ch = i & 127;
        pwt[tap][ch] = pw[(size_t)(cbase + ch) * 9 + tap];
    }
    __syncthreads();
    const int c4 = tid & 31;
    const int tg = tid >> 5;
    const int cq = cbase + c4 * 4;
    float4 pb4 = *(const float4*)(pb + cq);
    #pragma unroll
    for (int j = 0; j < 4; ++j) {
        int tt = tg * 4 + j;
        int t = t0 + tt;
        int w = w0 + tt;
        float4 a = *(const float4*)(x2t + (size_t)t * C_ + cq);
        a.x += pb4.x; a.y += pb4.y; a.z += pb4.z; a.w += pb4.w;
        #pragma unroll
        for (int dh = -1; dh <= 1; ++dh) {
            int hh = h + dh;
            if (hh < 0 || hh >= H_) continue;
            #pragma unroll
            for (int dw = -1; dw <= 1; ++dw) {
                int ww = w + dw;
                if (ww < 0 || ww >= W_) continue;
                float4 xv = *(const float4*)(x2t + (size_t)(t + dh * W_ + dw) * C_ + cq);
                float4 wvv = *(const float4*)&pwt[(dh + 1) * 3 + (dw + 1)][c4 * 4];
                a.x += wvv.x * xv.x; a.y += wvv.y * xv.y;
                a.z += wvv.z * xv.z; a.w += wvv.w * xv.w;
            }
        }
        *(float4*)&tile[tt][c4 * 4] = a;
    }
    __syncthreads();
    const int ch = tid >> 1, hf = (tid & 1) * 16;
    float* drow = outp + ((size_t)b * C_ + cbase + ch) * HW_ + hw0 + hf;
    #pragma unroll
    for (int qq = 0; qq < 4; ++qq) {
        float4 vv = make_float4(tile[hf + qq * 4 + 0][ch], tile[hf + qq * 4 + 1][ch],
                                tile[hf + qq * 4 + 2][ch], tile[hf + qq * 4 + 3][ch]);
        *(float4*)(drow + qq * 4) = vv;
    }
}

// ============================ launcher ============================
extern "C" void kernel_launch(void* const* d_in, const int* in_sizes, int n_in,
                              void* d_out, int out_size, void* d_ws, size_t ws_size,
                              hipStream_t stream)
{
    (void)in_sizes; (void)n_in; (void)out_size; (void)ws_size;
    const float* x         = (const float*)d_in[0];
    const float* ln1_g     = (const float*)d_in[1];
    const float* ln1_b     = (const float*)d_in[2];
    const float* conv_in_w = (const float*)d_in[3];
    const float* conv_in_b = (const float*)d_in[4];
    const float* qkv_h_w   = (const float*)d_in[5];
    const float* qkv_h_b   = (const float*)d_in[6];
    const float* qkv_v_w   = (const float*)d_in[7];
    const float* qkv_v_b   = (const float*)d_in[8];
    const float* fuse_w    = (const float*)d_in[9];
    const float* fuse_b    = (const float*)d_in[10];
    const float* ln2_g     = (const float*)d_in[11];
    const float* ln2_b     = (const float*)d_in[12];
    const float* fc1_w     = (const float*)d_in[13];
    const float* fc1_b     = (const float*)d_in[14];
    const float* fc2_w     = (const float*)d_in[15];
    const float* fc2_b     = (const float*)d_in[16];
    const float* peg_w     = (const float*)d_in[17];
    const float* peg_b     = (const float*)d_in[18];
    float* outp = (float*)d_out;

    // workspace (~204 MB)
    float* wsf   = (float*)d_ws;
    float* mean1 = wsf;
    float* rstd1 = wsf + (size_t)T_;
    float* x1    = wsf + 2 * (size_t)T_;                           // [T,256] f32
    unsigned short* xn = (unsigned short*)x1;                      // [T,256] bf16
    unsigned short* ci = (unsigned short*)(x1 + (size_t)T_ * 128); // [T,256] bf16
    unsigned short* ah = (unsigned short*)(x1 + (size_t)T_ * 256); // [T,128] bf16
    unsigned short* av = ah + (size_t)T_ * 128;                    // [T,128] bf16
    unsigned short* xn2 = ah;                                      // [T,256] bf16 (post-fuse)
    unsigned short* qt = av + (size_t)T_ * 128;                    // chunk buf: 24576x1024 bf16
    unsigned short* wb = qt + (size_t)24576 * 1024;
    unsigned short* wconv = wb;
    unsigned short* wqh   = wconv + 65536;
    unsigned short* wqv   = wqh + 49152;
    unsigned short* wfu   = wqv + 49152;
    unsigned short* wf1   = wfu + 65536;
    unsigned short* wf2   = wf1 + 262144;

    dim3 blk(256);

    wcvt_kernel<<<dim3(64), blk, 0, stream>>>(conv_in_w, wconv, 65536);
    wcvt_kernel<<<dim3(48), blk, 0, stream>>>(qkv_h_w, wqh, 49152);
    wcvt_kernel<<<dim3(48), blk, 0, stream>>>(qkv_v_w, wqv, 49152);
    wcvt_kernel<<<dim3(64), blk, 0, stream>>>(fuse_w, wfu, 65536);
    wcvt_kernel<<<dim3(256), blk, 0, stream>>>(fc1_w, wf1, 262144);
    wcvt_kernel<<<dim3(256), blk, 0, stream>>>(fc2_w, wf2, 262144);
    // 1. LN1 stats + normalized bf16 row-major
    ln1_stats_kernel<<<dim3(T_ / 256), blk, 0, stream>>>(x, mean1, rstd1);
    xln_kernel<<<dim3(T_ / 32, 8), blk, 0, stream>>>(x, mean1, rstd1, ln1_g, ln1_b, xn);
    // 2. conv_in
    mgemm<AB_ROW, EB_BF16><<<dim3(768, 2), blk, 0, stream>>>(
        xn, nullptr, wconv, conv_in_b, nullptr, nullptr, ci, 256, 256, 256, 256, 0);
    // 3. horizontal attention: 2 chunks of 192 strips (49152 tokens)
    for (int ch = 0; ch < 2; ++ch) {
        const size_t r0 = (size_t)ch * 49152;
        mgemm<AB_ROW, EB_BF16><<<dim3(384, 3), blk, 0, stream>>>(
            ci + r0 * 256, nullptr, wqh, qkv_h_b, nullptr, nullptr, qt,
            128, 256, 128, 384, 0);
        attn_mfma_kernel<256, 0><<<dim3(192 * 8), blk, 0, stream>>>(qt, ah, ch * 192);
    }
    // 4. vertical attention: 2 chunks of 256 strips (49152 rows, (b,w,h) order)
    for (int cv = 0; cv < 2; ++cv) {
        mgemm<AB_GATHER, EB_BF16><<<dim3(384, 3), blk, 0, stream>>>(
            ci, nullptr, wqv, qkv_v_b, nullptr, nullptr, qt,
            128, 0, 128, 384, cv * 49152);
        attn_mfma_kernel<192, 1><<<dim3(256 * 8), blk, 0, stream>>>(qt, av, cv * 256);
    }
    // 5. fuse -> x1 (fp32) + planar residual x fused in epilogue
    mgemm<AB_CAT, ER_PLANAR><<<dim3(768, 2), blk, 0, stream>>>(
        ah, av, wfu, fuse_b, x, x1, nullptr, 256, 128, 256, 256, 0);
    // 6. LN2 fused stats+normalize -> xn2 (bf16, overwrites ah/av)
    ln2norm_kernel<<<dim3(T_ / 4), blk, 0, stream>>>(x1, ln2_g, ln2_b, xn2);
    // 7. FFN: 4 token chunks of 24576 rows, in-place residual into x1
    for (int cs = 0; cs < 4; ++cs) {
        const size_t r0 = (size_t)cs * 24576;
        mgemm<AB_ROW, EG_BF16><<<dim3(192, 8), blk, 0, stream>>>(
            xn2 + r0 * 256, nullptr, wf1, fc1_b, nullptr, nullptr, qt,
            256, 256, 256, 1024, 0);
        mgemm<AB_ROW, ER_F32><<<dim3(192, 2), blk, 0, stream>>>(
            qt, nullptr, wf2, fc2_b, x1 + r0 * 256, x1 + r0 * 256, nullptr,
            1024, 1024, 1024, 256, 0);
    }
    // 8. PEG + residual -> planar output
    peg_kernel<<<dim3(T_ / 32, 2), blk, 0, stream>>>(x1, peg_w, peg_b, outp);
}